// Round 16
// baseline (1779.342 us; speedup 1.0000x reference)
//
#include <hip/hip_runtime.h>
#include <math.h>

#define NN 3072
#define EPSG 1e-20f
#define EDGE_CAP 53248          // ~47.2K expected edges + margin
#define RCH 128                 // rows per chunk
#define NCH 24                  // chunks (24*128 = 3072)
typedef unsigned long long u64;

// ---------- prep 1: rowsum0[i] = sum_c adj[i][c] ----------
__global__ __launch_bounds__(256) void rowsum_kernel(const float* __restrict__ adj,
                                                     float* __restrict__ rowsum) {
    int row = blockIdx.x;
    const float* r = adj + (size_t)row * NN;
    float s = 0.f;
    for (int c = threadIdx.x; c < NN; c += 256) s += r[c];
#pragma unroll
    for (int off = 32; off > 0; off >>= 1) s += __shfl_down(s, off);
    __shared__ float ps[4];
    if ((threadIdx.x & 63) == 0) ps[threadIdx.x >> 6] = s;
    __syncthreads();
    if (threadIdx.x == 0) rowsum[row] = (ps[0] + ps[1]) + (ps[2] + ps[3]);
}

// ---------- prep 2a: per-chunk column counts ----------
__global__ __launch_bounds__(256) void cnt_kernel(const float* __restrict__ adj,
                                                  unsigned* __restrict__ cnt) {
    int c = blockIdx.x * 256 + threadIdx.x;
    const float* col = adj + (size_t)(blockIdx.y * RCH) * NN + c;
    unsigned n = 0;
#pragma unroll 4
    for (int i = 0; i < RCH; ++i)
        n += (col[(size_t)i * NN] != 0.0f) ? 1u : 0u;
    cnt[blockIdx.y * NN + c] = n;
}

// ---------- prep 2b: total per-column counts ----------
__global__ __launch_bounds__(256) void colsum_kernel(const unsigned* __restrict__ cnt,
                                                     unsigned* __restrict__ colcnt) {
    int c = blockIdx.x * 256 + threadIdx.x;
    unsigned n = 0;
    for (int by = 0; by < NCH; ++by) n += cnt[by * NN + c];
    colcnt[c] = n;
}

// ---------- prep 2c: exclusive scan of column counts (1 wave) ----------
__global__ __launch_bounds__(64) void scan_kernel(const unsigned* __restrict__ colcnt,
                                                  unsigned* __restrict__ eoff) {
    int lane = threadIdx.x;
    unsigned tot = 0;
    for (int k = 0; k < 48; ++k) tot += colcnt[lane * 48 + k];
    unsigned x = tot;
    for (int off = 1; off < 64; off <<= 1) {
        unsigned y = __shfl_up(x, off);
        if (lane >= off) x += y;
    }
    unsigned run = x - tot;
    for (int k = 0; k < 48; ++k) {
        unsigned c = colcnt[lane * 48 + k];
        eoff[lane * 48 + k] = run;
        run += c;
    }
    if (lane == 63) eoff[NN] = run;
}

// ---------- prep 2d: per-(chunk,column) start offsets ----------
__global__ __launch_bounds__(256) void choff_kernel(const unsigned* __restrict__ cnt,
                                                    const unsigned* __restrict__ eoff,
                                                    unsigned* __restrict__ choff) {
    int c = blockIdx.x * 256 + threadIdx.x;
    unsigned run = eoff[c];
    for (int by = 0; by < NCH; ++by) {
        choff[by * NN + c] = run;
        run += cnt[by * NN + c];
    }
}

// ---------- prep 2e: fill CSC edge lists ----------
__global__ __launch_bounds__(256) void fill2_kernel(const float* __restrict__ adj,
                                                    const unsigned* __restrict__ choff,
                                                    unsigned short* __restrict__ edges) {
    int c = blockIdx.x * 256 + threadIdx.x;
    int r0 = blockIdx.y * RCH;
    unsigned off = choff[blockIdx.y * NN + c];
    const float* col = adj + (size_t)r0 * NN + c;
    for (int i = 0; i < RCH; ++i) {
        if (col[(size_t)i * NN] != 0.0f) {
            if (off < EDGE_CAP) edges[off] = (unsigned short)(r0 + i);
            ++off;
        }
    }
}

// monotonic order-preserving float->u32 map (never 0 for finite inputs)
__device__ __forceinline__ unsigned enc32(float v) {
    unsigned u = __float_as_uint(v);
    return (u & 0x80000000u) ? ~u : (u | 0x80000000u);
}

// ---------- prep 3: gumbel + derived per-node arrays ----------
__global__ __launch_bounds__(256) void gumbel_kernel(const float* __restrict__ logits,
                                                     const float* __restrict__ unif,
                                                     const float* __restrict__ rowsum,
                                                     float* __restrict__ out,
                                                     float* __restrict__ elog,
                                                     unsigned* __restrict__ keyenc,
                                                     unsigned* __restrict__ indeg) {
    int j = blockIdx.x * 256 + threadIdx.x;
    float lg = logits[j];
    float u  = unif[j];
    float g  = lg + (-logf(-logf(u + EPSG) + EPSG));
    out[NN + j] = g;                 // gumbel_logits output
    elog[j] = expf(lg);
    keyenc[j] = enc32(g);
    indeg[j] = (unsigned)(int)rowsum[j];
}

// ---------- prep 4: rank[j] = #{i: key[i]>key[j]} + #{i<j: key[i]==key[j]} ----------
__global__ __launch_bounds__(256) void rank_kernel(const unsigned* __restrict__ keyenc,
                                                   unsigned* __restrict__ rank,
                                                   unsigned* __restrict__ perm) {
    int j = blockIdx.x;
    unsigned kj = keyenc[j];
    unsigned cnt = 0;
    for (int i = threadIdx.x; i < NN; i += 256) {
        unsigned ki = keyenc[i];
        cnt += (ki > kj || (ki == kj && i < j)) ? 1u : 0u;
    }
#pragma unroll
    for (int off = 32; off > 0; off >>= 1) cnt += __shfl_down(cnt, off);
    __shared__ unsigned ps[4];
    if ((threadIdx.x & 63) == 0) ps[threadIdx.x >> 6] = cnt;
    __syncthreads();
    if (threadIdx.x == 0) {
        unsigned r = ps[0] + ps[1] + ps[2] + ps[3];
        rank[j] = r;
        perm[r] = (unsigned)j;
    }
}

// ---------- prep 5: scatter per-node state into rank order ----------
__global__ __launch_bounds__(256) void scatter_kernel(const unsigned* __restrict__ rank,
                                                      const unsigned* __restrict__ eoff,
                                                      const float* __restrict__ elog,
                                                      const unsigned* __restrict__ indeg,
                                                      unsigned* __restrict__ metaR,
                                                      float* __restrict__ elogR,
                                                      unsigned* __restrict__ indegR) {
    int j = blockIdx.x * 256 + threadIdx.x;
    unsigned r = rank[j];
    unsigned e0 = eoff[j];
    unsigned d = eoff[j + 1] - e0;
    metaR[r] = e0 | (d << 20);
    elogR[r] = elog[j];
    indegR[r] = indeg[j];
}

// ---------- prep 6: translate edge targets node->rank ----------
__global__ __launch_bounds__(256) void etrans_kernel(const unsigned short* __restrict__ edges,
                                                     const unsigned* __restrict__ rank,
                                                     unsigned short* __restrict__ edgesR) {
    int i = blockIdx.x * 256 + threadIdx.x;
    if (i < EDGE_CAP + 128) {
        unsigned e = edges[i];
        e = e < NN ? e : NN - 1;          // clamp garbage beyond true total
        edgesR[i] = (unsigned short)rank[e];
    }
}

__device__ __forceinline__ float wsum_f32(float v) {
    int t;
    t = __builtin_amdgcn_update_dpp(0, __float_as_int(v), 0x111, 0xf, 0xf, true); v += __int_as_float(t);
    t = __builtin_amdgcn_update_dpp(0, __float_as_int(v), 0x112, 0xf, 0xf, true); v += __int_as_float(t);
    t = __builtin_amdgcn_update_dpp(0, __float_as_int(v), 0x114, 0xf, 0xf, true); v += __int_as_float(t);
    t = __builtin_amdgcn_update_dpp(0, __float_as_int(v), 0x118, 0xf, 0xf, true); v += __int_as_float(t);
    t = __builtin_amdgcn_update_dpp(0, __float_as_int(v), 0x142, 0xf, 0xf, true); v += __int_as_float(t);
    t = __builtin_amdgcn_update_dpp(0, __float_as_int(v), 0x143, 0xf, 0xf, true); v += __int_as_float(t);
    return v;
}
__device__ __forceinline__ int rdlane(int v, int l) { return __builtin_amdgcn_readlane(v, l); }
__device__ __forceinline__ u64 rdlane64(u64 v, int l) {
    unsigned lo = (unsigned)rdlane((int)(unsigned)v, l);
    unsigned hi = (unsigned)rdlane((int)(unsigned)(v >> 32), l);
    return ((u64)hi << 32) | lo;
}
__device__ __forceinline__ int div48(int j) { return ((j >> 4) * 21846) >> 16; }  // exact for j<3072

// ---------- sequential topo-sort: rank-indexed, batched (B=4) ----------
__global__ __launch_bounds__(256) void topo_kernel(const float* __restrict__ elogR,
                                                   const unsigned* __restrict__ indegR,
                                                   const unsigned* __restrict__ metaR,
                                                   const unsigned short* __restrict__ edgesR,
                                                   const unsigned* __restrict__ perm,
                                                   float* __restrict__ gslog,
                                                   unsigned* __restrict__ gssel,
                                                   float* __restrict__ out) {
    __shared__ unsigned       s_indeg[NN];              // keyed by rank
    __shared__ float          s_elog[NN];
    __shared__ unsigned       s_meta[NN];               // eoff | d<<20
    __shared__ unsigned short s_edges[EDGE_CAP + 128];  // rank targets

    const int tid = threadIdx.x;

    // ---- cooperative staging (all 4 waves) ----
    for (int x = tid; x < NN / 4; x += 256) {
        ((uint4*)s_indeg)[x] = ((const uint4*)indegR)[x];
        ((float4*)s_elog)[x] = ((const float4*)elogR)[x];
        ((uint4*)s_meta)[x]  = ((const uint4*)metaR)[x];
    }
    for (int x = tid; x < (EDGE_CAP + 128) / 8; x += 256)
        ((uint4*)s_edges)[x] = ((const uint4*)edgesR)[x];
    __syncthreads();
    if (tid >= 64) return;              // wave 0 continues alone
    const int lane = tid;
    const int base48 = lane * 48;       // lane owns ranks [48l, 48l+48)

    // ---- init: eligibility mask + S ----
    u64 mask = 0ULL;
    float S;
    {
        float ssl = 0.f;
        for (int i = 0; i < 48; ++i) {
            int r = base48 + i;
            if (s_indeg[r] == 0u) { mask |= 1ULL << i; ssl += s_elog[r]; }
        }
        float tot = wsum_f32(ssl);
        S = __int_as_float(rdlane(__float_as_int(tot), 63));
    }

    int t = 0;
    int guard = 0;
    while (t < NN) {
        if (++guard > NN + 8) break;    // safety

        // ---- formation: up to 4 lowest eligible ranks (rank order = lane order) ----
        int rb0 = 0x7FFFFFFF, rb1 = 0x7FFFFFFF, rb2 = 0x7FFFFFFF, rb3 = 0x7FFFFFFF;
        int formed = 0;
        unsigned e00 = 0, e01 = 0, e02 = 0, e03 = 0;
        int d0 = 0, d1 = 0, d2 = 0, d3 = 0;
#pragma unroll
        for (int b = 0; b < 4; ++b) {
            u64 ball = __ballot(mask != 0ULL);
            if (ball == 0ULL) break;
            int gl = (int)__ffsll(ball) - 1;
            u64 mg = rdlane64(mask, gl);
            int bit = (int)__ffsll(mg) - 1;
            int r = gl * 48 + bit;
            if (lane == gl) mask &= ~(1ULL << bit);
            unsigned m = s_meta[r];           // uniform read
            unsigned e0 = m & 0xFFFFFu;
            int dd = (int)(m >> 20);
            if (b == 0) { rb0 = r; e00 = e0; d0 = dd; }
            else if (b == 1) { rb1 = r; e01 = e0; d1 = dd; }
            else if (b == 2) { rb2 = r; e02 = e0; d2 = dd; }
            else { rb3 = r; e03 = e0; d3 = dd; }
            formed = b + 1;
            if (dd > 64) break;               // monster col ends the batch
        }
        if (formed == 0) break;

        // ---- edge gathers (pipelined) ----
        int ew0 = 0, ew1 = 0, ew2 = 0, ew3 = 0;
        if (formed > 0) ew0 = (int)s_edges[e00 + (lane < d0 ? lane : 0)];
        if (formed > 1) ew1 = (int)s_edges[e01 + (lane < d1 ? lane : 0)];
        if (formed > 2) ew2 = (int)s_edges[e02 + (lane < d2 ? lane : 0)];
        if (formed > 3) ew3 = (int)s_edges[e03 + (lane < d3 ? lane : 0)];

        // ---- all atomics issued back-to-back (DS ops execute in program order) ----
        unsigned o0 = 0xFFFFFFFFu, o1 = 0xFFFFFFFFu, o2 = 0xFFFFFFFFu, o3 = 0xFFFFFFFFu;
        if (formed > 0 && lane < d0) o0 = atomicSub(&s_indeg[ew0], 1u);
        if (formed > 1 && lane < d1) o1 = atomicSub(&s_indeg[ew1], 1u);
        if (formed > 2 && lane < d2) o2 = atomicSub(&s_indeg[ew2], 1u);
        if (formed > 3 && lane < d3) o3 = atomicSub(&s_indeg[ew3], 1u);

        // ---- apply steps serially; abort when an insertion outranks the next col ----
        int done = formed;
        int minins = 0x7FFFFFFF;
#pragma unroll
        for (int b = 0; b < 4; ++b) {
            if (b < done) {
                int rb = b == 0 ? rb0 : b == 1 ? rb1 : b == 2 ? rb2 : rb3;
                int dd = b == 0 ? d0 : b == 1 ? d1 : b == 2 ? d2 : d3;
                int ew = b == 0 ? ew0 : b == 1 ? ew1 : b == 2 ? ew2 : ew3;
                unsigned oo = b == 0 ? o0 : b == 1 ? o1 : b == 2 ? o2 : o3;
                unsigned e0f = b == 0 ? e00 : b == 1 ? e01 : b == 2 ? e02 : e03;

                if (lane == 0) { gslog[t + b] = S; gssel[t + b] = (unsigned)rb; }
                S -= s_elog[rb];                          // uniform read

                int pend = (lane < dd && oo == 1u) ? ew : -1;
                u64 ib = __ballot(pend >= 0);
                while (ib) {
                    int src = (int)__ffsll(ib) - 1; ib &= ib - 1;
                    int rr = rdlane(pend, src);
                    int og = div48(rr);
                    if (lane == og) mask |= 1ULL << (rr - 48 * og);
                    minins = rr < minins ? rr : minins;
                    S += s_elog[rr];
                }

                // monster col (always last in batch): extra atomic rounds
                if (dd > 64) {
                    for (int base = 64; base < dd; base += 64) {
                        int idx = base + lane;
                        int p2 = -1;
                        if (idx < dd) {
                            int rr2 = (int)s_edges[e0f + idx];
                            unsigned oo2 = atomicSub(&s_indeg[rr2], 1u);
                            if (oo2 == 1u) p2 = rr2;
                        }
                        u64 ib2 = __ballot(p2 >= 0);
                        while (ib2) {
                            int src = (int)__ffsll(ib2) - 1; ib2 &= ib2 - 1;
                            int rr = rdlane(p2, src);
                            int og = div48(rr);
                            if (lane == og) mask |= 1ULL << (rr - 48 * og);
                            minins = rr < minins ? rr : minins;
                            S += s_elog[rr];
                        }
                    }
                }

                if (b + 1 < done) {
                    int rnext = b == 0 ? rb1 : b == 1 ? rb2 : rb3;
                    if (minins < rnext) done = b + 1;     // uniform
                }
            }
        }

        // ---- rollback aborted columns (rare) ----
        if (done < formed) {
#pragma unroll
            for (int b = 1; b < 4; ++b) {
                if (b >= done && b < formed) {
                    int rb = b == 1 ? rb1 : b == 2 ? rb2 : rb3;
                    int dd = b == 1 ? d1 : b == 2 ? d2 : d3;
                    int ew = b == 1 ? ew1 : b == 2 ? ew2 : ew3;
                    if (lane < dd) atomicAdd(&s_indeg[ew], 1u);
                    int og = div48(rb);
                    if (lane == og) mask |= 1ULL << (rb - 48 * og);
                }
            }
        }

        t += done;
    }

    // ---- epilogue: all log_probs in parallel (rank -> node via perm) ----
    for (int i = lane; i < NN; i += 64) {
        unsigned rr = gssel[i];
        float Si = gslog[i];
        int node = (int)perm[rr];
        out[node] = -logf((1.0f / s_elog[rr]) * Si + 1e-10f);
    }
}

extern "C" void kernel_launch(void* const* d_in, const int* in_sizes, int n_in,
                              void* d_out, int out_size, void* d_ws, size_t ws_size,
                              hipStream_t stream) {
    const float* logits = (const float*)d_in[0];
    const float* adj    = (const float*)d_in[1];
    const float* unif   = (const float*)d_in[2];
    float* out = (float*)d_out;

    char* ws = (char*)d_ws;
    float*          rowsum = (float*)(ws + 0);
    unsigned*       cnt    = (unsigned*)(ws + 16384);
    unsigned*       colcnt = (unsigned*)(ws + 311296);
    unsigned*       eoff   = (unsigned*)(ws + 323584);
    unsigned*       choff  = (unsigned*)(ws + 339968);
    unsigned short* edges  = (unsigned short*)(ws + 634880);   // EDGE_CAP u16
    float*          elog   = (float*)(ws + 741376);
    unsigned*       keyenc = (unsigned*)(ws + 753664);
    unsigned*       indeg  = (unsigned*)(ws + 765952);
    unsigned*       rank   = (unsigned*)(ws + 778240);
    unsigned*       perm   = (unsigned*)(ws + 790528);
    unsigned*       metaR  = (unsigned*)(ws + 802816);
    float*          elogR  = (float*)(ws + 815104);
    unsigned*       indegR = (unsigned*)(ws + 827392);
    unsigned short* edgesR = (unsigned short*)(ws + 839680);   // EDGE_CAP+128 u16
    float*          gslog  = (float*)(ws + 946432);
    unsigned*       gssel  = (unsigned*)(ws + 958720);         // ends 971,008

    rowsum_kernel<<<NN, 256, 0, stream>>>(adj, rowsum);
    cnt_kernel<<<dim3(NN / 256, NCH), 256, 0, stream>>>(adj, cnt);
    colsum_kernel<<<NN / 256, 256, 0, stream>>>(cnt, colcnt);
    scan_kernel<<<1, 64, 0, stream>>>(colcnt, eoff);
    choff_kernel<<<NN / 256, 256, 0, stream>>>(cnt, eoff, choff);
    fill2_kernel<<<dim3(NN / 256, NCH), 256, 0, stream>>>(adj, choff, edges);
    gumbel_kernel<<<NN / 256, 256, 0, stream>>>(logits, unif, rowsum, out,
                                                elog, keyenc, indeg);
    rank_kernel<<<NN, 256, 0, stream>>>(keyenc, rank, perm);
    scatter_kernel<<<NN / 256, 256, 0, stream>>>(rank, eoff, elog, indeg,
                                                 metaR, elogR, indegR);
    etrans_kernel<<<(EDGE_CAP + 128 + 255) / 256, 256, 0, stream>>>(edges, rank, edgesR);
    topo_kernel<<<1, 256, 0, stream>>>(elogR, indegR, metaR, edgesR, perm,
                                       gslog, gssel, out);
}

// Round 17
// 1586.701 us; speedup vs baseline: 1.1214x; 1.1214x over previous
//
#include <hip/hip_runtime.h>
#include <math.h>

#define NN 3072
#define EPSG 1e-20f
#define EDGE_CAP 53248          // ~47.2K expected edges + margin
#define RCH 128                 // rows per chunk
#define NCH 24                  // chunks (24*128 = 3072)
typedef unsigned long long u64;

// ---------- prep 1: rowsum0[i] = sum_c adj[i][c] ----------
__global__ __launch_bounds__(256) void rowsum_kernel(const float* __restrict__ adj,
                                                     float* __restrict__ rowsum) {
    int row = blockIdx.x;
    const float* r = adj + (size_t)row * NN;
    float s = 0.f;
    for (int c = threadIdx.x; c < NN; c += 256) s += r[c];
#pragma unroll
    for (int off = 32; off > 0; off >>= 1) s += __shfl_down(s, off);
    __shared__ float ps[4];
    if ((threadIdx.x & 63) == 0) ps[threadIdx.x >> 6] = s;
    __syncthreads();
    if (threadIdx.x == 0) rowsum[row] = (ps[0] + ps[1]) + (ps[2] + ps[3]);
}

// ---------- prep 2a: per-chunk column counts ----------
__global__ __launch_bounds__(256) void cnt_kernel(const float* __restrict__ adj,
                                                  unsigned* __restrict__ cnt) {
    int c = blockIdx.x * 256 + threadIdx.x;
    const float* col = adj + (size_t)(blockIdx.y * RCH) * NN + c;
    unsigned n = 0;
#pragma unroll 4
    for (int i = 0; i < RCH; ++i)
        n += (col[(size_t)i * NN] != 0.0f) ? 1u : 0u;
    cnt[blockIdx.y * NN + c] = n;
}

// ---------- prep 2b: total per-column counts ----------
__global__ __launch_bounds__(256) void colsum_kernel(const unsigned* __restrict__ cnt,
                                                     unsigned* __restrict__ colcnt) {
    int c = blockIdx.x * 256 + threadIdx.x;
    unsigned n = 0;
    for (int by = 0; by < NCH; ++by) n += cnt[by * NN + c];
    colcnt[c] = n;
}

// ---------- prep 2c: exclusive scan of column counts (1 wave) ----------
__global__ __launch_bounds__(64) void scan_kernel(const unsigned* __restrict__ colcnt,
                                                  unsigned* __restrict__ eoff) {
    int lane = threadIdx.x;
    unsigned tot = 0;
    for (int k = 0; k < 48; ++k) tot += colcnt[lane * 48 + k];
    unsigned x = tot;
    for (int off = 1; off < 64; off <<= 1) {
        unsigned y = __shfl_up(x, off);
        if (lane >= off) x += y;
    }
    unsigned run = x - tot;
    for (int k = 0; k < 48; ++k) {
        unsigned c = colcnt[lane * 48 + k];
        eoff[lane * 48 + k] = run;
        run += c;
    }
    if (lane == 63) eoff[NN] = run;
}

// ---------- prep 2d: per-(chunk,column) start offsets ----------
__global__ __launch_bounds__(256) void choff_kernel(const unsigned* __restrict__ cnt,
                                                    const unsigned* __restrict__ eoff,
                                                    unsigned* __restrict__ choff) {
    int c = blockIdx.x * 256 + threadIdx.x;
    unsigned run = eoff[c];
    for (int by = 0; by < NCH; ++by) {
        choff[by * NN + c] = run;
        run += cnt[by * NN + c];
    }
}

// ---------- prep 2e: fill CSC edge lists ----------
__global__ __launch_bounds__(256) void fill2_kernel(const float* __restrict__ adj,
                                                    const unsigned* __restrict__ choff,
                                                    unsigned short* __restrict__ edges) {
    int c = blockIdx.x * 256 + threadIdx.x;
    int r0 = blockIdx.y * RCH;
    unsigned off = choff[blockIdx.y * NN + c];
    const float* col = adj + (size_t)r0 * NN + c;
    for (int i = 0; i < RCH; ++i) {
        if (col[(size_t)i * NN] != 0.0f) {
            if (off < EDGE_CAP) edges[off] = (unsigned short)(r0 + i);
            ++off;
        }
    }
}

// monotonic order-preserving float->u32 map (never 0 for finite inputs)
__device__ __forceinline__ unsigned enc32(float v) {
    unsigned u = __float_as_uint(v);
    return (u & 0x80000000u) ? ~u : (u | 0x80000000u);
}

// ---------- prep 3: gumbel + derived per-node arrays ----------
__global__ __launch_bounds__(256) void gumbel_kernel(const float* __restrict__ logits,
                                                     const float* __restrict__ unif,
                                                     const float* __restrict__ rowsum,
                                                     float* __restrict__ out,
                                                     float* __restrict__ elog,
                                                     unsigned* __restrict__ keyenc,
                                                     unsigned* __restrict__ indeg) {
    int j = blockIdx.x * 256 + threadIdx.x;
    float lg = logits[j];
    float u  = unif[j];
    float g  = lg + (-logf(-logf(u + EPSG) + EPSG));
    out[NN + j] = g;                 // gumbel_logits output
    elog[j] = expf(lg);
    keyenc[j] = enc32(g);
    indeg[j] = (unsigned)(int)rowsum[j];
}

// ---------- prep 4: rank[j] = #{i: key[i]>key[j]} + #{i<j: key[i]==key[j]} ----------
__global__ __launch_bounds__(256) void rank_kernel(const unsigned* __restrict__ keyenc,
                                                   unsigned* __restrict__ rank,
                                                   unsigned* __restrict__ perm) {
    int j = blockIdx.x;
    unsigned kj = keyenc[j];
    unsigned cnt = 0;
    for (int i = threadIdx.x; i < NN; i += 256) {
        unsigned ki = keyenc[i];
        cnt += (ki > kj || (ki == kj && i < j)) ? 1u : 0u;
    }
#pragma unroll
    for (int off = 32; off > 0; off >>= 1) cnt += __shfl_down(cnt, off);
    __shared__ unsigned ps[4];
    if ((threadIdx.x & 63) == 0) ps[threadIdx.x >> 6] = cnt;
    __syncthreads();
    if (threadIdx.x == 0) {
        unsigned r = ps[0] + ps[1] + ps[2] + ps[3];
        rank[j] = r;
        perm[r] = (unsigned)j;
    }
}

// ---------- prep 5: scatter per-node state into rank order ----------
__global__ __launch_bounds__(256) void scatter_kernel(const unsigned* __restrict__ rank,
                                                      const unsigned* __restrict__ eoff,
                                                      const float* __restrict__ elog,
                                                      const unsigned* __restrict__ indeg,
                                                      unsigned* __restrict__ metaR,
                                                      float* __restrict__ elogR,
                                                      unsigned* __restrict__ indegR) {
    int j = blockIdx.x * 256 + threadIdx.x;
    unsigned r = rank[j];
    unsigned e0 = eoff[j];
    unsigned d = eoff[j + 1] - e0;
    metaR[r] = e0 | (d << 20);
    elogR[r] = elog[j];
    indegR[r] = indeg[j];
}

// ---------- prep 6: translate edge targets node->rank ----------
__global__ __launch_bounds__(256) void etrans_kernel(const unsigned short* __restrict__ edges,
                                                     const unsigned* __restrict__ rank,
                                                     unsigned short* __restrict__ edgesR) {
    int i = blockIdx.x * 256 + threadIdx.x;
    if (i < EDGE_CAP + 128) {
        unsigned e = edges[i];
        e = e < NN ? e : NN - 1;          // clamp garbage beyond true total
        edgesR[i] = (unsigned short)rank[e];
    }
}

__device__ __forceinline__ int rdlane(int v, int l) { return __builtin_amdgcn_readlane(v, l); }
__device__ __forceinline__ u64 rdlane64(u64 v, int l) {
    unsigned lo = (unsigned)rdlane((int)(unsigned)v, l);
    unsigned hi = (unsigned)rdlane((int)(unsigned)(v >> 32), l);
    return ((u64)hi << 32) | lo;
}
__device__ __forceinline__ int div48(int j) { return ((j >> 4) * 21846) >> 16; }  // exact for j<3072

// two lowest set ranks across all lanes' masks (uniform result)
__device__ __forceinline__ void two_lowest(u64 mask, int& r1, int& r2) {
    r1 = 0x7FFFFFFF; r2 = 0x7FFFFFFF;
    u64 ball = __ballot(mask != 0ULL);
    if (ball) {
        int gl1 = (int)__ffsll(ball) - 1;
        u64 mg1 = rdlane64(mask, gl1);
        int b1 = (int)__ffsll(mg1) - 1;
        r1 = gl1 * 48 + b1;
        u64 mg1r = mg1 & (mg1 - 1);
        if (mg1r) {
            r2 = gl1 * 48 + (int)__ffsll(mg1r) - 1;
        } else {
            u64 ball2 = ball & (ball - 1);
            if (ball2) {
                int gl2 = (int)__ffsll(ball2) - 1;
                u64 mg2 = rdlane64(mask, gl2);
                r2 = gl2 * 48 + (int)__ffsll(mg2) - 1;
            }
        }
    }
}

// ---------- sequential topo-sort: rank-indexed, 2-deep column cache ----------
__global__ __launch_bounds__(256) void topo_kernel(const float* __restrict__ elogR,
                                                   const unsigned* __restrict__ indegR,
                                                   const unsigned* __restrict__ metaR,
                                                   const unsigned short* __restrict__ edgesR,
                                                   const unsigned* __restrict__ perm,
                                                   float* __restrict__ out) {
    __shared__ unsigned       s_indeg[NN];               // keyed by rank
    __shared__ float          s_elog[NN];
    __shared__ unsigned       s_meta[NN];                // eoff | d<<20 (reused as diff[] after loop)
    __shared__ unsigned short s_instime[NN];             // step when became eligible
    __shared__ unsigned short s_seltime[NN];             // step when selected
    __shared__ unsigned short s_edges[EDGE_CAP + 128];   // rank targets

    const int tid = threadIdx.x;

    // ---- cooperative staging (all 4 waves) ----
    for (int x = tid; x < NN / 4; x += 256) {
        uint4 dg = ((const uint4*)indegR)[x];
        ((uint4*)s_indeg)[x] = dg;
        ((float4*)s_elog)[x] = ((const float4*)elogR)[x];
        ((uint4*)s_meta)[x]  = ((const uint4*)metaR)[x];
        ushort4 it;
        it.x = dg.x ? (unsigned short)NN : 0;
        it.y = dg.y ? (unsigned short)NN : 0;
        it.z = dg.z ? (unsigned short)NN : 0;
        it.w = dg.w ? (unsigned short)NN : 0;
        ((ushort4*)s_instime)[x] = it;
    }
    for (int x = tid; x < (EDGE_CAP + 128) / 8; x += 256)
        ((uint4*)s_edges)[x] = ((const uint4*)edgesR)[x];
    __syncthreads();
    if (tid >= 64) return;              // wave 0 continues alone
    const int lane = tid;
    const int base48 = lane * 48;       // lane owns ranks [48l, 48l+48)

    // ---- init: eligibility mask ----
    u64 mask = 0ULL;
    for (int i = 0; i < 48; ++i)
        if (s_indeg[base48 + i] == 0u) mask |= 1ULL << i;

    // column loader: uniform r -> (e0, d) + per-lane edge word
    // (defined inline via macro-like lambda for register results)
#define LOAD_COL(r, E0, D, EW)                                         \
    {                                                                  \
        int rc_ = (unsigned)(r) < NN ? (r) : 0;                        \
        unsigned m_ = s_meta[rc_];                                     \
        E0 = m_ & 0xFFFFFu;                                            \
        D = ((unsigned)(r) < NN) ? (int)(m_ >> 20) : 0;                \
        EW = (int)s_edges[E0 + (lane < D ? lane : 0)];                 \
    }

    // ---- prime: current + 2-deep cache ----
    int r_cur, rA, rB;
    {
        int r1, r2;
        two_lowest(mask, r1, r2);
        r_cur = r1;
        int og = div48(r_cur);
        if (lane == og) mask &= ~(1ULL << (r_cur - 48 * og));
        two_lowest(mask, rA, rB);
    }
    unsigned eC0, eA0, eB0; int dC, dA, dB, ewC, ewA, ewB;
    LOAD_COL(r_cur, eC0, dC, ewC);
    LOAD_COL(rA, eA0, dA, ewA);
    LOAD_COL(rB, eB0, dB, ewB);

    for (int t = 0; t < NN; ++t) {
        if (lane == 0) s_seltime[r_cur] = (unsigned short)t;

        // ---- decrement this column's targets ----
        bool act = lane < dC;
        unsigned old = 0xFFFFFFFFu;
        if (act) old = atomicSub(&s_indeg[ewC], 1u);
        int pend = (act && old == 1u) ? ewC : -1;
        if (pend >= 0) s_instime[pend] = (unsigned short)(t + 1);

        // ---- merge insertions: mask bits + min rank ----
        int min_ins = 0x7FFFFFFF;
        u64 ib = __ballot(pend >= 0);
        while (ib) {
            int src = (int)__ffsll(ib) - 1; ib &= ib - 1;
            int rr = rdlane(pend, src);
            int og = div48(rr);
            if (lane == og) mask |= 1ULL << (rr - 48 * og);
            min_ins = rr < min_ins ? rr : min_ins;
        }

        // rare: degree > 64
        if (dC > 64) {
            for (int base = 64; base < dC; base += 64) {
                int idx = base + lane;
                int p2 = -1;
                if (idx < dC) {
                    int rr2 = (int)s_edges[eC0 + idx];
                    unsigned o2 = atomicSub(&s_indeg[rr2], 1u);
                    if (o2 == 1u) { p2 = rr2; s_instime[rr2] = (unsigned short)(t + 1); }
                }
                u64 ib2 = __ballot(p2 >= 0);
                while (ib2) {
                    int src = (int)__ffsll(ib2) - 1; ib2 &= ib2 - 1;
                    int rr = rdlane(p2, src);
                    int og = div48(rr);
                    if (lane == og) mask |= 1ULL << (rr - 48 * og);
                    min_ins = rr < min_ins ? rr : min_ins;
                }
            }
        }

        if (t + 1 >= NN) break;

        // ---- next selection ----
        int next = rA < min_ins ? rA : min_ins;
        {
            int og = div48(next);
            if (lane == og) mask &= ~(1ULL << (next - 48 * og));
        }
        bool hitA = (next == rA);
        if (hitA) { eC0 = eA0; dC = dA; ewC = ewA; }
        else LOAD_COL(next, eC0, dC, ewC);          // rare serial reload

        // ---- rebuild 2-deep cache ----
        int r1, r2;
        two_lowest(mask, r1, r2);
        unsigned nA0, nB0; int ndA, ndB, nAe, nBe;
        if (r1 == rB)            { nA0 = eB0; ndA = dB; nAe = ewB; }
        else if (r1 == rA && !hitA) { nA0 = eA0; ndA = dA; nAe = ewA; }
        else LOAD_COL(r1, nA0, ndA, nAe);
        if (r2 == rB)            { nB0 = eB0; ndB = dB; nBe = ewB; }
        else if (r2 == rA && !hitA) { nB0 = eA0; ndB = dA; nBe = ewA; }
        else LOAD_COL(r2, nB0, ndB, nBe);           // common: the one load (2 iters slack)
        rA = r1; eA0 = nA0; dA = ndA; ewA = nAe;
        rB = r2; eB0 = nB0; dB = ndB; ewB = nBe;
        r_cur = next;
    }

    // ---- epilogue 1: build diff array (reuse s_meta as float diff[NN]) ----
    float* diff = (float*)s_meta;
    for (int i = lane; i < NN; i += 64) diff[i] = 0.f;
    for (int i = lane; i < NN; i += 64) {
        float e = s_elog[i];
        int it = (int)s_instime[i];
        int st = (int)s_seltime[i];
        atomicAdd(&diff[it], e);
        if (st + 1 < NN) atomicAdd(&diff[st + 1], -e);
    }
    // ---- epilogue 2: inclusive prefix -> S_t in place ----
    float base = 0.f;
    for (int c = 0; c < NN / 64; ++c) {
        float v = diff[c * 64 + lane];
#pragma unroll
        for (int off = 1; off < 64; off <<= 1) {
            float y = __shfl_up(v, off);
            if (lane >= off) v += y;
        }
        v += base;
        diff[c * 64 + lane] = v;
        base = __shfl(v, 63);
    }
    // ---- epilogue 3: outputs ----
    for (int i = lane; i < NN; i += 64) {
        int tau = (int)s_seltime[i];
        float Si = diff[tau];
        out[perm[i]] = -logf(Si / s_elog[i] + 1e-10f);
    }
#undef LOAD_COL
}

extern "C" void kernel_launch(void* const* d_in, const int* in_sizes, int n_in,
                              void* d_out, int out_size, void* d_ws, size_t ws_size,
                              hipStream_t stream) {
    const float* logits = (const float*)d_in[0];
    const float* adj    = (const float*)d_in[1];
    const float* unif   = (const float*)d_in[2];
    float* out = (float*)d_out;

    char* ws = (char*)d_ws;
    float*          rowsum = (float*)(ws + 0);
    unsigned*       cnt    = (unsigned*)(ws + 16384);
    unsigned*       colcnt = (unsigned*)(ws + 311296);
    unsigned*       eoff   = (unsigned*)(ws + 323584);
    unsigned*       choff  = (unsigned*)(ws + 339968);
    unsigned short* edges  = (unsigned short*)(ws + 634880);   // EDGE_CAP u16
    float*          elog   = (float*)(ws + 741376);
    unsigned*       keyenc = (unsigned*)(ws + 753664);
    unsigned*       indeg  = (unsigned*)(ws + 765952);
    unsigned*       rank   = (unsigned*)(ws + 778240);
    unsigned*       perm   = (unsigned*)(ws + 790528);
    unsigned*       metaR  = (unsigned*)(ws + 802816);
    float*          elogR  = (float*)(ws + 815104);
    unsigned*       indegR = (unsigned*)(ws + 827392);
    unsigned short* edgesR = (unsigned short*)(ws + 839680);   // EDGE_CAP+128 u16

    rowsum_kernel<<<NN, 256, 0, stream>>>(adj, rowsum);
    cnt_kernel<<<dim3(NN / 256, NCH), 256, 0, stream>>>(adj, cnt);
    colsum_kernel<<<NN / 256, 256, 0, stream>>>(cnt, colcnt);
    scan_kernel<<<1, 64, 0, stream>>>(colcnt, eoff);
    choff_kernel<<<NN / 256, 256, 0, stream>>>(cnt, eoff, choff);
    fill2_kernel<<<dim3(NN / 256, NCH), 256, 0, stream>>>(adj, choff, edges);
    gumbel_kernel<<<NN / 256, 256, 0, stream>>>(logits, unif, rowsum, out,
                                                elog, keyenc, indeg);
    rank_kernel<<<NN, 256, 0, stream>>>(keyenc, rank, perm);
    scatter_kernel<<<NN / 256, 256, 0, stream>>>(rank, eoff, elog, indeg,
                                                 metaR, elogR, indegR);
    etrans_kernel<<<(EDGE_CAP + 128 + 255) / 256, 256, 0, stream>>>(edges, rank, edgesR);
    topo_kernel<<<1, 256, 0, stream>>>(elogR, indegR, metaR, edgesR, perm, out);
}

// Round 18
// 1372.011 us; speedup vs baseline: 1.2969x; 1.1565x over previous
//
#include <hip/hip_runtime.h>
#include <math.h>

#define NN 3072
#define EPSG 1e-20f
#define EDGE_CAP 53248          // ~47.2K expected edges + margin
#define RCH 128                 // rows per chunk
#define NCH 24                  // chunks (24*128 = 3072)
typedef unsigned long long u64;

// ---------- prep 1: rowsum0[i] = sum_c adj[i][c] ----------
__global__ __launch_bounds__(256) void rowsum_kernel(const float* __restrict__ adj,
                                                     float* __restrict__ rowsum) {
    int row = blockIdx.x;
    const float* r = adj + (size_t)row * NN;
    float s = 0.f;
    for (int c = threadIdx.x; c < NN; c += 256) s += r[c];
#pragma unroll
    for (int off = 32; off > 0; off >>= 1) s += __shfl_down(s, off);
    __shared__ float ps[4];
    if ((threadIdx.x & 63) == 0) ps[threadIdx.x >> 6] = s;
    __syncthreads();
    if (threadIdx.x == 0) rowsum[row] = (ps[0] + ps[1]) + (ps[2] + ps[3]);
}

// ---------- prep 2a: per-chunk column counts ----------
__global__ __launch_bounds__(256) void cnt_kernel(const float* __restrict__ adj,
                                                  unsigned* __restrict__ cnt) {
    int c = blockIdx.x * 256 + threadIdx.x;
    const float* col = adj + (size_t)(blockIdx.y * RCH) * NN + c;
    unsigned n = 0;
#pragma unroll 4
    for (int i = 0; i < RCH; ++i)
        n += (col[(size_t)i * NN] != 0.0f) ? 1u : 0u;
    cnt[blockIdx.y * NN + c] = n;
}

// ---------- prep 2b: total per-column counts ----------
__global__ __launch_bounds__(256) void colsum_kernel(const unsigned* __restrict__ cnt,
                                                     unsigned* __restrict__ colcnt) {
    int c = blockIdx.x * 256 + threadIdx.x;
    unsigned n = 0;
    for (int by = 0; by < NCH; ++by) n += cnt[by * NN + c];
    colcnt[c] = n;
}

// ---------- prep 2c: exclusive scan of column counts (1 wave) ----------
__global__ __launch_bounds__(64) void scan_kernel(const unsigned* __restrict__ colcnt,
                                                  unsigned* __restrict__ eoff) {
    int lane = threadIdx.x;
    unsigned tot = 0;
    for (int k = 0; k < 48; ++k) tot += colcnt[lane * 48 + k];
    unsigned x = tot;
    for (int off = 1; off < 64; off <<= 1) {
        unsigned y = __shfl_up(x, off);
        if (lane >= off) x += y;
    }
    unsigned run = x - tot;
    for (int k = 0; k < 48; ++k) {
        unsigned c = colcnt[lane * 48 + k];
        eoff[lane * 48 + k] = run;
        run += c;
    }
    if (lane == 63) eoff[NN] = run;
}

// ---------- prep 2d: per-(chunk,column) start offsets ----------
__global__ __launch_bounds__(256) void choff_kernel(const unsigned* __restrict__ cnt,
                                                    const unsigned* __restrict__ eoff,
                                                    unsigned* __restrict__ choff) {
    int c = blockIdx.x * 256 + threadIdx.x;
    unsigned run = eoff[c];
    for (int by = 0; by < NCH; ++by) {
        choff[by * NN + c] = run;
        run += cnt[by * NN + c];
    }
}

// ---------- prep 2e: fill CSC edge lists ----------
__global__ __launch_bounds__(256) void fill2_kernel(const float* __restrict__ adj,
                                                    const unsigned* __restrict__ choff,
                                                    unsigned short* __restrict__ edges) {
    int c = blockIdx.x * 256 + threadIdx.x;
    int r0 = blockIdx.y * RCH;
    unsigned off = choff[blockIdx.y * NN + c];
    const float* col = adj + (size_t)r0 * NN + c;
    for (int i = 0; i < RCH; ++i) {
        if (col[(size_t)i * NN] != 0.0f) {
            if (off < EDGE_CAP) edges[off] = (unsigned short)(r0 + i);
            ++off;
        }
    }
}

// monotonic order-preserving float->u32 map (never 0 for finite inputs)
__device__ __forceinline__ unsigned enc32(float v) {
    unsigned u = __float_as_uint(v);
    return (u & 0x80000000u) ? ~u : (u | 0x80000000u);
}

// ---------- prep 3: gumbel + derived per-node arrays ----------
__global__ __launch_bounds__(256) void gumbel_kernel(const float* __restrict__ logits,
                                                     const float* __restrict__ unif,
                                                     const float* __restrict__ rowsum,
                                                     float* __restrict__ out,
                                                     float* __restrict__ elog,
                                                     unsigned* __restrict__ keyenc,
                                                     unsigned* __restrict__ indeg) {
    int j = blockIdx.x * 256 + threadIdx.x;
    float lg = logits[j];
    float u  = unif[j];
    float g  = lg + (-logf(-logf(u + EPSG) + EPSG));
    out[NN + j] = g;                 // gumbel_logits output
    elog[j] = expf(lg);
    keyenc[j] = enc32(g);
    indeg[j] = (unsigned)(int)rowsum[j];
}

// ---------- prep 4: rank[j] = #{i: key[i]>key[j]} + #{i<j: key[i]==key[j]} ----------
__global__ __launch_bounds__(256) void rank_kernel(const unsigned* __restrict__ keyenc,
                                                   unsigned* __restrict__ rank,
                                                   unsigned* __restrict__ perm) {
    int j = blockIdx.x;
    unsigned kj = keyenc[j];
    unsigned cnt = 0;
    for (int i = threadIdx.x; i < NN; i += 256) {
        unsigned ki = keyenc[i];
        cnt += (ki > kj || (ki == kj && i < j)) ? 1u : 0u;
    }
#pragma unroll
    for (int off = 32; off > 0; off >>= 1) cnt += __shfl_down(cnt, off);
    __shared__ unsigned ps[4];
    if ((threadIdx.x & 63) == 0) ps[threadIdx.x >> 6] = cnt;
    __syncthreads();
    if (threadIdx.x == 0) {
        unsigned r = ps[0] + ps[1] + ps[2] + ps[3];
        rank[j] = r;
        perm[r] = (unsigned)j;
    }
}

// ---------- prep 5: scatter per-node state into rank order ----------
__global__ __launch_bounds__(256) void scatter_kernel(const unsigned* __restrict__ rank,
                                                      const unsigned* __restrict__ eoff,
                                                      const float* __restrict__ elog,
                                                      const unsigned* __restrict__ indeg,
                                                      unsigned* __restrict__ metaR,
                                                      float* __restrict__ elogR,
                                                      unsigned* __restrict__ indegR) {
    int j = blockIdx.x * 256 + threadIdx.x;
    unsigned r = rank[j];
    unsigned e0 = eoff[j];
    unsigned d = eoff[j + 1] - e0;
    metaR[r] = e0 | (d << 20);
    elogR[r] = elog[j];
    indegR[r] = indeg[j];
}

// ---------- prep 6: translate edge targets node->rank ----------
__global__ __launch_bounds__(256) void etrans_kernel(const unsigned short* __restrict__ edges,
                                                     const unsigned* __restrict__ rank,
                                                     unsigned short* __restrict__ edgesR) {
    int i = blockIdx.x * 256 + threadIdx.x;
    if (i < EDGE_CAP + 128) {
        unsigned e = edges[i];
        e = e < NN ? e : NN - 1;          // clamp garbage beyond true total
        edgesR[i] = (unsigned short)rank[e];
    }
}

__device__ __forceinline__ int rdlane(int v, int l) { return __builtin_amdgcn_readlane(v, l); }
__device__ __forceinline__ u64 rdlane64(u64 v, int l) {
    unsigned lo = (unsigned)rdlane((int)(unsigned)v, l);
    unsigned hi = (unsigned)rdlane((int)(unsigned)(v >> 32), l);
    return ((u64)hi << 32) | lo;
}
__device__ __forceinline__ int div48(int j) { return ((j >> 4) * 21846) >> 16; }  // exact for j<3072

// DPP wave64 min-reduce (identity-safe: old=v, bound_ctrl=false); result in lane 63
__device__ __forceinline__ unsigned wmin_u32(unsigned v) {
    unsigned t;
    t = (unsigned)__builtin_amdgcn_update_dpp((int)v, (int)v, 0x111, 0xf, 0xf, false); v = t < v ? t : v;
    t = (unsigned)__builtin_amdgcn_update_dpp((int)v, (int)v, 0x112, 0xf, 0xf, false); v = t < v ? t : v;
    t = (unsigned)__builtin_amdgcn_update_dpp((int)v, (int)v, 0x114, 0xf, 0xf, false); v = t < v ? t : v;
    t = (unsigned)__builtin_amdgcn_update_dpp((int)v, (int)v, 0x118, 0xf, 0xf, false); v = t < v ? t : v;
    t = (unsigned)__builtin_amdgcn_update_dpp((int)v, (int)v, 0x142, 0xf, 0xf, false); v = t < v ? t : v;
    t = (unsigned)__builtin_amdgcn_update_dpp((int)v, (int)v, 0x143, 0xf, 0xf, false); v = t < v ? t : v;
    return v;
}

// ---------- sequential topo-sort: R15 structure, S moved to epilogue ----------
__global__ __launch_bounds__(256) void topo_kernel(const float* __restrict__ elogR,
                                                   const unsigned* __restrict__ indegR,
                                                   const unsigned* __restrict__ metaR,
                                                   const unsigned short* __restrict__ edgesR,
                                                   const unsigned* __restrict__ perm,
                                                   float* __restrict__ out) {
    __shared__ unsigned       s_indeg[NN];               // keyed by rank
    __shared__ float          s_elog[NN];
    __shared__ unsigned       s_meta[NN];                // eoff | d<<20 (reused as diff[] after loop)
    __shared__ unsigned short s_instime[NN];             // step when became eligible
    __shared__ unsigned short s_seltime[NN];             // step when selected
    __shared__ unsigned short s_edges[EDGE_CAP + 128];   // rank targets

    const int tid = threadIdx.x;

    // ---- cooperative staging (all 4 waves) ----
    for (int x = tid; x < NN / 4; x += 256) {
        ((uint4*)s_indeg)[x] = ((const uint4*)indegR)[x];
        ((float4*)s_elog)[x] = ((const float4*)elogR)[x];
        ((uint4*)s_meta)[x]  = ((const uint4*)metaR)[x];
        ushort4 z; z.x = 0; z.y = 0; z.z = 0; z.w = 0;
        ((ushort4*)s_instime)[x] = z;                    // init 0 (overwritten on insertion)
    }
    for (int x = tid; x < (EDGE_CAP + 128) / 8; x += 256)
        ((uint4*)s_edges)[x] = ((const uint4*)edgesR)[x];
    __syncthreads();
    if (tid >= 64) return;              // wave 0 continues alone
    const int lane = tid;
    const int base48 = lane * 48;       // lane owns ranks [48l, 48l+48)

    // ---- init: eligibility mask ----
    u64 mask = 0ULL;
    for (int i = 0; i < 48; ++i)
        if (s_indeg[base48 + i] == 0u) mask |= 1ULL << i;

    // ---- first selection = lowest eligible rank ----
    int r_cur;
    {
        u64 ball = __ballot(mask != 0ULL);
        int gl = (int)__ffsll(ball) - 1;
        u64 mg = rdlane64(mask, gl);
        r_cur = gl * 48 + (int)__ffsll(mg) - 1;
    }
    {
        int og = div48(r_cur);
        if (lane == og) mask &= ~(1ULL << (r_cur - 48 * og));
    }
    unsigned m0 = s_meta[r_cur];
    unsigned e0_cur = m0 & 0xFFFFFu;
    int d = (int)(m0 >> 20);
    int ew = (int)s_edges[e0_cur + (lane < d ? lane : 0)];

    // ---- spec = next-lowest eligible rank + prefetch its column ----
    int spec_rank; unsigned e0s; int ds; int ews;
    {
        u64 ball = __ballot(mask != 0ULL);
        u64 bb = ball ? ball : 1ULL;
        int gl = (int)__ffsll(bb) - 1;
        u64 mg = rdlane64(mask, gl);
        u64 mg2 = mg ? mg : 1ULL;
        spec_rank = ball ? (gl * 48 + (int)__ffsll(mg2) - 1) : 0x7FFFFFFF;
        int sc = spec_rank < NN ? spec_rank : 0;
        unsigned ms = s_meta[sc];
        e0s = ms & 0xFFFFFu; ds = (int)(ms >> 20);
        ews = (int)s_edges[e0s + (lane < ds ? lane : 0)];
    }

    for (int t = 0; t < NN; ++t) {
        if (lane == 0) s_seltime[r_cur] = (unsigned short)t;

        // ---- atomic decrement of this column's targets (edges pre-loaded) ----
        bool act = lane < d;
        unsigned old = 0xFFFFFFFFu;
        if (act) old = atomicSub(&s_indeg[ew], 1u);
        bool ins = act && (old == 1u);
        int pend = ins ? ew : 0x7FFFFFFF;
        if (ins) s_instime[ew] = (unsigned short)(t + 1);

        // ---- min inserted rank: branchless DPP reduce ----
        int min_ins = (int)(unsigned)rdlane((int)wmin_u32((unsigned)pend), 63);

        // ---- mask updates (usually 0-1 passes) ----
        u64 ib = __ballot(ins);
        while (ib) {
            int src = (int)__ffsll(ib) - 1; ib &= ib - 1;
            int rr = rdlane(pend, src);
            int og = div48(rr);
            if (lane == og) mask |= 1ULL << (rr - 48 * og);
        }

        // rare slow path: degree > 64
        if (d > 64) {
            for (int base = 64; base < d; base += 64) {
                int idx = base + lane;
                int p2 = -1;
                if (idx < d) {
                    int rr2 = (int)s_edges[e0_cur + idx];
                    unsigned o2 = atomicSub(&s_indeg[rr2], 1u);
                    if (o2 == 1u) { p2 = rr2; s_instime[rr2] = (unsigned short)(t + 1); }
                }
                u64 ib2 = __ballot(p2 >= 0);
                while (ib2) {
                    int src = (int)__ffsll(ib2) - 1; ib2 &= ib2 - 1;
                    int rr = rdlane(p2, src);
                    int og = div48(rr);
                    if (lane == og) mask |= 1ULL << (rr - 48 * og);
                    min_ins = rr < min_ins ? rr : min_ins;
                }
            }
        }

        // ---- next = min(spec, best insertion) ----
        int next = spec_rank < min_ins ? spec_rank : min_ins;

        int dn; int ewn; unsigned e0n;
        if (next != spec_rank) {
            // spec miss (rare, uniform): serial reload
            int nc = next < NN ? next : 0;
            unsigned m = s_meta[nc];
            e0n = m & 0xFFFFFu; dn = (int)(m >> 20);
            ewn = (int)s_edges[e0n + (lane < dn ? lane : 0)];
        } else { e0n = e0s; dn = ds; ewn = ews; }

        // clear next's bit
        if ((unsigned)next < NN) {
            int og = div48(next);
            if (lane == og) mask &= ~(1ULL << (next - 48 * og));
        }

        // ---- spec2 = new lowest eligible + prefetch (covered by next iter) ----
        {
            u64 ball = __ballot(mask != 0ULL);
            u64 bb = ball ? ball : 1ULL;
            int gl = (int)__ffsll(bb) - 1;
            u64 mg = rdlane64(mask, gl);
            u64 mg2 = mg ? mg : 1ULL;
            spec_rank = ball ? (gl * 48 + (int)__ffsll(mg2) - 1) : 0x7FFFFFFF;
            int sc = spec_rank < NN ? spec_rank : 0;
            unsigned ms = s_meta[sc];
            e0s = ms & 0xFFFFFu; ds = (int)(ms >> 20);
            ews = (int)s_edges[e0s + (lane < ds ? lane : 0)];
        }

        r_cur = next; d = dn; ew = ewn; e0_cur = e0n;
    }

    // ---- epilogue 1: build diff array (reuse s_meta as float diff[NN]) ----
    float* diff = (float*)s_meta;
    for (int i = lane; i < NN; i += 64) diff[i] = 0.f;
    for (int i = lane; i < NN; i += 64) {
        float e = s_elog[i];
        int it = (int)s_instime[i];
        int st = (int)s_seltime[i];
        atomicAdd(&diff[it], e);
        if (st + 1 < NN) atomicAdd(&diff[st + 1], -e);
    }
    // ---- epilogue 2: inclusive prefix -> S_t in place ----
    float base = 0.f;
    for (int c = 0; c < NN / 64; ++c) {
        float v = diff[c * 64 + lane];
#pragma unroll
        for (int off = 1; off < 64; off <<= 1) {
            float y = __shfl_up(v, off);
            if (lane >= off) v += y;
        }
        v += base;
        diff[c * 64 + lane] = v;
        base = __shfl(v, 63);
    }
    // ---- epilogue 3: outputs ----
    for (int i = lane; i < NN; i += 64) {
        int tau = (int)s_seltime[i];
        float Si = diff[tau];
        out[perm[i]] = -logf(Si / s_elog[i] + 1e-10f);
    }
}

extern "C" void kernel_launch(void* const* d_in, const int* in_sizes, int n_in,
                              void* d_out, int out_size, void* d_ws, size_t ws_size,
                              hipStream_t stream) {
    const float* logits = (const float*)d_in[0];
    const float* adj    = (const float*)d_in[1];
    const float* unif   = (const float*)d_in[2];
    float* out = (float*)d_out;

    char* ws = (char*)d_ws;
    float*          rowsum = (float*)(ws + 0);
    unsigned*       cnt    = (unsigned*)(ws + 16384);
    unsigned*       colcnt = (unsigned*)(ws + 311296);
    unsigned*       eoff   = (unsigned*)(ws + 323584);
    unsigned*       choff  = (unsigned*)(ws + 339968);
    unsigned short* edges  = (unsigned short*)(ws + 634880);   // EDGE_CAP u16
    float*          elog   = (float*)(ws + 741376);
    unsigned*       keyenc = (unsigned*)(ws + 753664);
    unsigned*       indeg  = (unsigned*)(ws + 765952);
    unsigned*       rank   = (unsigned*)(ws + 778240);
    unsigned*       perm   = (unsigned*)(ws + 790528);
    unsigned*       metaR  = (unsigned*)(ws + 802816);
    float*          elogR  = (float*)(ws + 815104);
    unsigned*       indegR = (unsigned*)(ws + 827392);
    unsigned short* edgesR = (unsigned short*)(ws + 839680);   // EDGE_CAP+128 u16

    rowsum_kernel<<<NN, 256, 0, stream>>>(adj, rowsum);
    cnt_kernel<<<dim3(NN / 256, NCH), 256, 0, stream>>>(adj, cnt);
    colsum_kernel<<<NN / 256, 256, 0, stream>>>(cnt, colcnt);
    scan_kernel<<<1, 64, 0, stream>>>(colcnt, eoff);
    choff_kernel<<<NN / 256, 256, 0, stream>>>(cnt, eoff, choff);
    fill2_kernel<<<dim3(NN / 256, NCH), 256, 0, stream>>>(adj, choff, edges);
    gumbel_kernel<<<NN / 256, 256, 0, stream>>>(logits, unif, rowsum, out,
                                                elog, keyenc, indeg);
    rank_kernel<<<NN, 256, 0, stream>>>(keyenc, rank, perm);
    scatter_kernel<<<NN / 256, 256, 0, stream>>>(rank, eoff, elog, indeg,
                                                 metaR, elogR, indegR);
    etrans_kernel<<<(EDGE_CAP + 128 + 255) / 256, 256, 0, stream>>>(edges, rank, edgesR);
    topo_kernel<<<1, 256, 0, stream>>>(elogR, indegR, metaR, edgesR, perm, out);
}

// Round 19
// 1255.505 us; speedup vs baseline: 1.4172x; 1.0928x over previous
//
#include <hip/hip_runtime.h>
#include <math.h>

#define NN 3072
#define EPSG 1e-20f
#define EDGE_CAP 53248          // ~47.2K expected edges + margin
#define RCH 128                 // rows per chunk
#define NCH 24                  // chunks (24*128 = 3072)
typedef unsigned long long u64;

// ---------- prep 1: rowsum0[i] = sum_c adj[i][c] ----------
__global__ __launch_bounds__(256) void rowsum_kernel(const float* __restrict__ adj,
                                                     float* __restrict__ rowsum) {
    int row = blockIdx.x;
    const float* r = adj + (size_t)row * NN;
    float s = 0.f;
    for (int c = threadIdx.x; c < NN; c += 256) s += r[c];
#pragma unroll
    for (int off = 32; off > 0; off >>= 1) s += __shfl_down(s, off);
    __shared__ float ps[4];
    if ((threadIdx.x & 63) == 0) ps[threadIdx.x >> 6] = s;
    __syncthreads();
    if (threadIdx.x == 0) rowsum[row] = (ps[0] + ps[1]) + (ps[2] + ps[3]);
}

// ---------- prep 2a: per-chunk column counts ----------
__global__ __launch_bounds__(256) void cnt_kernel(const float* __restrict__ adj,
                                                  unsigned* __restrict__ cnt) {
    int c = blockIdx.x * 256 + threadIdx.x;
    const float* col = adj + (size_t)(blockIdx.y * RCH) * NN + c;
    unsigned n = 0;
#pragma unroll 4
    for (int i = 0; i < RCH; ++i)
        n += (col[(size_t)i * NN] != 0.0f) ? 1u : 0u;
    cnt[blockIdx.y * NN + c] = n;
}

// ---------- prep 2b: total per-column counts ----------
__global__ __launch_bounds__(256) void colsum_kernel(const unsigned* __restrict__ cnt,
                                                     unsigned* __restrict__ colcnt) {
    int c = blockIdx.x * 256 + threadIdx.x;
    unsigned n = 0;
    for (int by = 0; by < NCH; ++by) n += cnt[by * NN + c];
    colcnt[c] = n;
}

// ---------- prep 2c: exclusive scan of column counts (1 wave) ----------
__global__ __launch_bounds__(64) void scan_kernel(const unsigned* __restrict__ colcnt,
                                                  unsigned* __restrict__ eoff) {
    int lane = threadIdx.x;
    unsigned tot = 0;
    for (int k = 0; k < 48; ++k) tot += colcnt[lane * 48 + k];
    unsigned x = tot;
    for (int off = 1; off < 64; off <<= 1) {
        unsigned y = __shfl_up(x, off);
        if (lane >= off) x += y;
    }
    unsigned run = x - tot;
    for (int k = 0; k < 48; ++k) {
        unsigned c = colcnt[lane * 48 + k];
        eoff[lane * 48 + k] = run;
        run += c;
    }
    if (lane == 63) eoff[NN] = run;
}

// ---------- prep 2d: per-(chunk,column) start offsets ----------
__global__ __launch_bounds__(256) void choff_kernel(const unsigned* __restrict__ cnt,
                                                    const unsigned* __restrict__ eoff,
                                                    unsigned* __restrict__ choff) {
    int c = blockIdx.x * 256 + threadIdx.x;
    unsigned run = eoff[c];
    for (int by = 0; by < NCH; ++by) {
        choff[by * NN + c] = run;
        run += cnt[by * NN + c];
    }
}

// ---------- prep 2e: fill CSC edge lists ----------
__global__ __launch_bounds__(256) void fill2_kernel(const float* __restrict__ adj,
                                                    const unsigned* __restrict__ choff,
                                                    unsigned short* __restrict__ edges) {
    int c = blockIdx.x * 256 + threadIdx.x;
    int r0 = blockIdx.y * RCH;
    unsigned off = choff[blockIdx.y * NN + c];
    const float* col = adj + (size_t)r0 * NN + c;
    for (int i = 0; i < RCH; ++i) {
        if (col[(size_t)i * NN] != 0.0f) {
            if (off < EDGE_CAP) edges[off] = (unsigned short)(r0 + i);
            ++off;
        }
    }
}

// monotonic order-preserving float->u32 map (never 0 for finite inputs)
__device__ __forceinline__ unsigned enc32(float v) {
    unsigned u = __float_as_uint(v);
    return (u & 0x80000000u) ? ~u : (u | 0x80000000u);
}

// ---------- prep 3: gumbel + derived per-node arrays ----------
__global__ __launch_bounds__(256) void gumbel_kernel(const float* __restrict__ logits,
                                                     const float* __restrict__ unif,
                                                     const float* __restrict__ rowsum,
                                                     float* __restrict__ out,
                                                     float* __restrict__ elog,
                                                     unsigned* __restrict__ keyenc,
                                                     unsigned* __restrict__ indeg) {
    int j = blockIdx.x * 256 + threadIdx.x;
    float lg = logits[j];
    float u  = unif[j];
    float g  = lg + (-logf(-logf(u + EPSG) + EPSG));
    out[NN + j] = g;                 // gumbel_logits output
    elog[j] = expf(lg);
    keyenc[j] = enc32(g);
    indeg[j] = (unsigned)(int)rowsum[j];
}

// ---------- prep 4: rank[j] = #{i: key[i]>key[j]} + #{i<j: key[i]==key[j]} ----------
__global__ __launch_bounds__(256) void rank_kernel(const unsigned* __restrict__ keyenc,
                                                   unsigned* __restrict__ rank,
                                                   unsigned* __restrict__ perm) {
    int j = blockIdx.x;
    unsigned kj = keyenc[j];
    unsigned cnt = 0;
    for (int i = threadIdx.x; i < NN; i += 256) {
        unsigned ki = keyenc[i];
        cnt += (ki > kj || (ki == kj && i < j)) ? 1u : 0u;
    }
#pragma unroll
    for (int off = 32; off > 0; off >>= 1) cnt += __shfl_down(cnt, off);
    __shared__ unsigned ps[4];
    if ((threadIdx.x & 63) == 0) ps[threadIdx.x >> 6] = cnt;
    __syncthreads();
    if (threadIdx.x == 0) {
        unsigned r = ps[0] + ps[1] + ps[2] + ps[3];
        rank[j] = r;
        perm[r] = (unsigned)j;
    }
}

// ---------- prep 5: scatter per-node state into rank order ----------
__global__ __launch_bounds__(256) void scatter_kernel(const unsigned* __restrict__ rank,
                                                      const unsigned* __restrict__ eoff,
                                                      const float* __restrict__ elog,
                                                      const unsigned* __restrict__ indeg,
                                                      unsigned* __restrict__ metaR,
                                                      float* __restrict__ elogR,
                                                      unsigned* __restrict__ indegR) {
    int j = blockIdx.x * 256 + threadIdx.x;
    unsigned r = rank[j];
    unsigned e0 = eoff[j];
    unsigned d = eoff[j + 1] - e0;
    metaR[r] = e0 | (d << 20);
    elogR[r] = elog[j];
    indegR[r] = indeg[j];
}

// ---------- prep 6: translate edge targets node->rank ----------
__global__ __launch_bounds__(256) void etrans_kernel(const unsigned short* __restrict__ edges,
                                                     const unsigned* __restrict__ rank,
                                                     unsigned short* __restrict__ edgesR) {
    int i = blockIdx.x * 256 + threadIdx.x;
    if (i < EDGE_CAP + 128) {
        unsigned e = edges[i];
        e = e < NN ? e : NN - 1;          // clamp garbage beyond true total
        edgesR[i] = (unsigned short)rank[e];
    }
}

__device__ __forceinline__ int rdlane(int v, int l) { return __builtin_amdgcn_readlane(v, l); }
__device__ __forceinline__ u64 rdlane64(u64 v, int l) {
    unsigned lo = (unsigned)rdlane((int)(unsigned)v, l);
    unsigned hi = (unsigned)rdlane((int)(unsigned)(v >> 32), l);
    return ((u64)hi << 32) | lo;
}
__device__ __forceinline__ int div48(int j) { return ((j >> 4) * 21846) >> 16; }  // exact for j<3072

// ---------- sequential topo-sort: R15 loop, S reconstructed in epilogue ----------
__global__ __launch_bounds__(256) void topo_kernel(const float* __restrict__ elogR,
                                                   const unsigned* __restrict__ indegR,
                                                   const unsigned* __restrict__ metaR,
                                                   const unsigned short* __restrict__ edgesR,
                                                   const unsigned* __restrict__ perm,
                                                   float* __restrict__ out) {
    __shared__ unsigned       s_indeg[NN];               // keyed by rank
    __shared__ float          s_elog[NN];
    __shared__ unsigned       s_meta[NN];                // eoff | d<<20 (reused as diff[] after loop)
    __shared__ unsigned short s_instime[NN];             // step when became eligible
    __shared__ unsigned short s_seltime[NN];             // step when selected
    __shared__ unsigned short s_edges[EDGE_CAP + 128];   // rank targets

    const int tid = threadIdx.x;

    // ---- cooperative staging (all 4 waves) ----
    for (int x = tid; x < NN / 4; x += 256) {
        ((uint4*)s_indeg)[x] = ((const uint4*)indegR)[x];
        ((float4*)s_elog)[x] = ((const float4*)elogR)[x];
        ((uint4*)s_meta)[x]  = ((const uint4*)metaR)[x];
        ushort4 z; z.x = 0; z.y = 0; z.z = 0; z.w = 0;
        ((ushort4*)s_instime)[x] = z;                    // 0 = eligible from start
    }
    for (int x = tid; x < (EDGE_CAP + 128) / 8; x += 256)
        ((uint4*)s_edges)[x] = ((const uint4*)edgesR)[x];
    __syncthreads();
    if (tid >= 64) return;              // wave 0 continues alone
    const int lane = tid;
    const int base48 = lane * 48;       // lane owns ranks [48l, 48l+48)

    // ---- init: eligibility mask ----
    u64 mask = 0ULL;
    for (int i = 0; i < 48; ++i)
        if (s_indeg[base48 + i] == 0u) mask |= 1ULL << i;

    // ---- first selection = lowest eligible rank ----
    int r_cur;
    {
        u64 ball = __ballot(mask != 0ULL);
        int gl = (int)__ffsll(ball) - 1;
        u64 mg = rdlane64(mask, gl);
        r_cur = gl * 48 + (int)__ffsll(mg) - 1;
    }
    {
        int og = div48(r_cur);
        if (lane == og) mask &= ~(1ULL << (r_cur - 48 * og));
    }
    unsigned m0 = s_meta[r_cur];
    unsigned e0_cur = m0 & 0xFFFFFu;
    int d = (int)(m0 >> 20);
    int ew = (int)s_edges[e0_cur + (lane < d ? lane : 0)];

    // ---- spec = next-lowest eligible rank + prefetch its column ----
    int spec_rank; unsigned e0s; int ds; int ews;
    {
        u64 ball = __ballot(mask != 0ULL);
        u64 bb = ball ? ball : 1ULL;
        int gl = (int)__ffsll(bb) - 1;
        u64 mg = rdlane64(mask, gl);
        u64 mg2 = mg ? mg : 1ULL;
        spec_rank = ball ? (gl * 48 + (int)__ffsll(mg2) - 1) : 0x7FFFFFFF;
        int sc = spec_rank < NN ? spec_rank : 0;
        unsigned ms = s_meta[sc];
        e0s = ms & 0xFFFFFu; ds = (int)(ms >> 20);
        ews = (int)s_edges[e0s + (lane < ds ? lane : 0)];
    }

    for (int t = 0; t < NN; ++t) {
        if (lane == 0) s_seltime[r_cur] = (unsigned short)t;

        // ---- atomic decrement of this column's targets (edges pre-loaded) ----
        bool act = lane < d;
        unsigned old = 0xFFFFFFFFu;
        if (act) old = atomicSub(&s_indeg[ew], 1u);
        bool ins = act && (old == 1u);
        int pend = ins ? ew : -1;
        if (ins) s_instime[ew] = (unsigned short)(t + 1);

        // ---- merge insertions: mask bits + min rank (sparse, avg ~1 pass) ----
        int min_ins = 0x7FFFFFFF;
        u64 ib = __ballot(ins);
        while (ib) {
            int src = (int)__ffsll(ib) - 1; ib &= ib - 1;
            int rr = rdlane(pend, src);
            int og = div48(rr);
            if (lane == og) mask |= 1ULL << (rr - 48 * og);
            min_ins = rr < min_ins ? rr : min_ins;
        }

        // rare slow path: degree > 64
        if (d > 64) {
            for (int base = 64; base < d; base += 64) {
                int idx = base + lane;
                int p2 = -1;
                if (idx < d) {
                    int rr2 = (int)s_edges[e0_cur + idx];
                    unsigned o2 = atomicSub(&s_indeg[rr2], 1u);
                    if (o2 == 1u) { p2 = rr2; s_instime[rr2] = (unsigned short)(t + 1); }
                }
                u64 ib2 = __ballot(p2 >= 0);
                while (ib2) {
                    int src = (int)__ffsll(ib2) - 1; ib2 &= ib2 - 1;
                    int rr = rdlane(p2, src);
                    int og = div48(rr);
                    if (lane == og) mask |= 1ULL << (rr - 48 * og);
                    min_ins = rr < min_ins ? rr : min_ins;
                }
            }
        }

        // ---- next = min(spec, best insertion) ----
        int next = spec_rank < min_ins ? spec_rank : min_ins;

        int dn; int ewn; unsigned e0n;
        if (next != spec_rank) {
            // spec miss (rare, uniform): serial reload
            int nc = next < NN ? next : 0;
            unsigned m = s_meta[nc];
            e0n = m & 0xFFFFFu; dn = (int)(m >> 20);
            ewn = (int)s_edges[e0n + (lane < dn ? lane : 0)];
        } else { e0n = e0s; dn = ds; ewn = ews; }

        // clear next's bit
        if ((unsigned)next < NN) {
            int og = div48(next);
            if (lane == og) mask &= ~(1ULL << (next - 48 * og));
        }

        // ---- spec2 = new lowest eligible + prefetch (covered by next iter) ----
        {
            u64 ball = __ballot(mask != 0ULL);
            u64 bb = ball ? ball : 1ULL;
            int gl = (int)__ffsll(bb) - 1;
            u64 mg = rdlane64(mask, gl);
            u64 mg2 = mg ? mg : 1ULL;
            spec_rank = ball ? (gl * 48 + (int)__ffsll(mg2) - 1) : 0x7FFFFFFF;
            int sc = spec_rank < NN ? spec_rank : 0;
            unsigned ms = s_meta[sc];
            e0s = ms & 0xFFFFFu; ds = (int)(ms >> 20);
            ews = (int)s_edges[e0s + (lane < ds ? lane : 0)];
        }

        r_cur = next; d = dn; ew = ewn; e0_cur = e0n;
    }

    // ---- epilogue 1: build diff array (reuse s_meta as float diff[NN]) ----
    float* diff = (float*)s_meta;
    for (int i = lane; i < NN; i += 64) diff[i] = 0.f;
    for (int i = lane; i < NN; i += 64) {
        float e = s_elog[i];
        int it = (int)s_instime[i];
        int st = (int)s_seltime[i];
        atomicAdd(&diff[it], e);
        if (st + 1 < NN) atomicAdd(&diff[st + 1], -e);
    }
    // ---- epilogue 2: inclusive prefix -> S_t in place ----
    float base = 0.f;
    for (int c = 0; c < NN / 64; ++c) {
        float v = diff[c * 64 + lane];
#pragma unroll
        for (int off = 1; off < 64; off <<= 1) {
            float y = __shfl_up(v, off);
            if (lane >= off) v += y;
        }
        v += base;
        diff[c * 64 + lane] = v;
        base = __shfl(v, 63);
    }
    // ---- epilogue 3: outputs ----
    for (int i = lane; i < NN; i += 64) {
        int tau = (int)s_seltime[i];
        float Si = diff[tau];
        out[perm[i]] = -logf(Si / s_elog[i] + 1e-10f);
    }
}

extern "C" void kernel_launch(void* const* d_in, const int* in_sizes, int n_in,
                              void* d_out, int out_size, void* d_ws, size_t ws_size,
                              hipStream_t stream) {
    const float* logits = (const float*)d_in[0];
    const float* adj    = (const float*)d_in[1];
    const float* unif   = (const float*)d_in[2];
    float* out = (float*)d_out;

    char* ws = (char*)d_ws;
    float*          rowsum = (float*)(ws + 0);
    unsigned*       cnt    = (unsigned*)(ws + 16384);
    unsigned*       colcnt = (unsigned*)(ws + 311296);
    unsigned*       eoff   = (unsigned*)(ws + 323584);
    unsigned*       choff  = (unsigned*)(ws + 339968);
    unsigned short* edges  = (unsigned short*)(ws + 634880);   // EDGE_CAP u16
    float*          elog   = (float*)(ws + 741376);
    unsigned*       keyenc = (unsigned*)(ws + 753664);
    unsigned*       indeg  = (unsigned*)(ws + 765952);
    unsigned*       rank   = (unsigned*)(ws + 778240);
    unsigned*       perm   = (unsigned*)(ws + 790528);
    unsigned*       metaR  = (unsigned*)(ws + 802816);
    float*          elogR  = (float*)(ws + 815104);
    unsigned*       indegR = (unsigned*)(ws + 827392);
    unsigned short* edgesR = (unsigned short*)(ws + 839680);   // EDGE_CAP+128 u16

    rowsum_kernel<<<NN, 256, 0, stream>>>(adj, rowsum);
    cnt_kernel<<<dim3(NN / 256, NCH), 256, 0, stream>>>(adj, cnt);
    colsum_kernel<<<NN / 256, 256, 0, stream>>>(cnt, colcnt);
    scan_kernel<<<1, 64, 0, stream>>>(colcnt, eoff);
    choff_kernel<<<NN / 256, 256, 0, stream>>>(cnt, eoff, choff);
    fill2_kernel<<<dim3(NN / 256, NCH), 256, 0, stream>>>(adj, choff, edges);
    gumbel_kernel<<<NN / 256, 256, 0, stream>>>(logits, unif, rowsum, out,
                                                elog, keyenc, indeg);
    rank_kernel<<<NN, 256, 0, stream>>>(keyenc, rank, perm);
    scatter_kernel<<<NN / 256, 256, 0, stream>>>(rank, eoff, elog, indeg,
                                                 metaR, elogR, indegR);
    etrans_kernel<<<(EDGE_CAP + 128 + 255) / 256, 256, 0, stream>>>(edges, rank, edgesR);
    topo_kernel<<<1, 256, 0, stream>>>(elogR, indegR, metaR, edgesR, perm, out);
}